// Round 11
// baseline (234.949 us; speedup 1.0000x reference)
//
#include <hip/hip_runtime.h>
#include <hip/hip_bf16.h>

using short4v = __attribute__((ext_vector_type(4))) short;
using short8 = __attribute__((ext_vector_type(8))) short;
using f32x4  = __attribute__((ext_vector_type(4))) float;

#define SEQ 2048
#define NHEAD 32
#define NKVH 4
#define HDIM 128
// 1/sqrt(128) * log2(e)  -- exp2-domain softmax, folded into Q at pack time
#define QK_SCALE_LOG2 (0.08838834764831845f * 1.44269504088896340f)

__device__ __forceinline__ float fast_exp2(float x) { return __builtin_amdgcn_exp2f(x); }
__device__ __forceinline__ float b2f(short u) {
    return __uint_as_float(((unsigned)(unsigned short)u) << 16);
}
__device__ __forceinline__ short f2bb(float f) {
    __hip_bfloat16 h = __float2bfloat16(f);
    return *reinterpret_cast<short*>(&h);
}
__device__ __forceinline__ void gload_lds16(const __hip_bfloat16* src, __hip_bfloat16* dst) {
    __builtin_amdgcn_global_load_lds((const __attribute__((address_space(1))) void*)src,
                                     (__attribute__((address_space(3))) void*)dst, 16, 0, 0);
}

// ---------------------------------------------------------------- fused prep: cast hs + transpose wq/wk/wv/wo
__global__ __launch_bounds__(256) void prep_kernel(
    const float* __restrict__ hs, __hip_bfloat16* __restrict__ hsb,
    const float* __restrict__ wq, const float* __restrict__ wk, const float* __restrict__ wv,
    const float* __restrict__ wo,
    __hip_bfloat16* __restrict__ WqkvT, __hip_bfloat16* __restrict__ WoT) {
    const int b = blockIdx.x, tid = threadIdx.x;
    if (b < 4096) {
        int i = b * 256 + tid;
        float4 v = ((const float4*)hs)[i];
        __hip_bfloat16 h4[4] = {__float2bfloat16(v.x), __float2bfloat16(v.y),
                                __float2bfloat16(v.z), __float2bfloat16(v.w)};
        ((ushort4*)hsb)[i] = *(ushort4*)h4;
        return;
    }
    __shared__ float tile[32][33];
    const float* W; __hip_bfloat16* Wt; int N, ld, nb, kb;
    if (b < 12288)      { int bb = b - 4096;  W = wq; Wt = WqkvT;                       N = 4096; ld = 2048; nb = (bb & 127) * 32; kb = (bb >> 7) * 32; }
    else if (b < 13312) { int bb = b - 12288; W = wk; Wt = WqkvT + (size_t)4096 * 2048; N = 512;  ld = 2048; nb = (bb & 15) * 32;  kb = (bb >> 4) * 32; }
    else if (b < 14336) { int bb = b - 13312; W = wv; Wt = WqkvT + (size_t)4608 * 2048; N = 512;  ld = 2048; nb = (bb & 15) * 32;  kb = (bb >> 4) * 32; }
    else                { int bb = b - 14336; W = wo; Wt = WoT;                         N = 2048; ld = 4096; nb = (bb & 63) * 32;  kb = (bb >> 6) * 32; }
    int tx = tid & 31, ty = tid >> 5;   // 32 x 8
    for (int j = 0; j < 32; j += 8)
        tile[ty + j][tx] = W[(size_t)(kb + ty + j) * N + nb + tx];
    __syncthreads();
    for (int j = 0; j < 32; j += 8)
        Wt[(size_t)(nb + ty + j) * ld + kb + tx] = __float2bfloat16(tile[tx][ty + j]);
}

// ---------------------------------------------------------------- 3-way bf16 partial add -> fp32 out
__global__ void add3b_kernel(const __hip_bfloat16* __restrict__ a, const __hip_bfloat16* __restrict__ b,
                             const __hip_bfloat16* __restrict__ c, float* __restrict__ o, int n4) {
    int i = blockIdx.x * blockDim.x + threadIdx.x;
    if (i >= n4) return;
    short4v x = ((const short4v*)a)[i];
    short4v y = ((const short4v*)b)[i];
    short4v z = ((const short4v*)c)[i];
    float4 r = {b2f(x[0]) + b2f(y[0]) + b2f(z[0]), b2f(x[1]) + b2f(y[1]) + b2f(z[1]),
                b2f(x[2]) + b2f(y[2]) + b2f(z[2]), b2f(x[3]) + b2f(y[3]) + b2f(z[3])};
    ((float4*)o)[i] = r;
}

// ---------------------------------------------------------------- GEMM: A(M,*)bf16 x Bt(N,*)bf16 -> C(M,N)
#define BM 128
#define BN 128
#define BKK 32
template <typename OutT>
__global__ __launch_bounds__(256) void gemm_bt_kernel(
    const __hip_bfloat16* __restrict__ A, const __hip_bfloat16* __restrict__ Bt,
    OutT* __restrict__ C, int M, int N, int KextMax, int ld, int koff, long long czstride, int Ktot) {
    const int kstart = blockIdx.z * koff;
    const int Kext = min(KextMax, Ktot - kstart);
    A  += (size_t)kstart;
    Bt += (size_t)kstart;
    C  += (size_t)blockIdx.z * czstride;
    __shared__ __align__(16) __hip_bfloat16 sA[BM * BKK];
    __shared__ __align__(16) __hip_bfloat16 sB[BN * BKK];
    const int tid = threadIdx.x;
    const int w = tid >> 6, l = tid & 63;
    const int wr = w >> 1, wc = w & 1;
    const int row0 = blockIdx.y * BM;
    const int col0 = blockIdx.x * BN;
    const int srow = l >> 2;          // 0..15
    const int scol = (l & 3) * 8;     // 0,8,16,24

    f32x4 acc[4][4] = {};
    const int fr = l & 15;
    const int fc = (l >> 4) * 8;

    for (int k0 = 0; k0 < Kext; k0 += BKK) {
        for (int i = 0; i < 2; ++i) {
            int c = i * 4 + w;  // chunk 0..7, 16 rows each
            gload_lds16(A + (size_t)(row0 + c * 16 + srow) * ld + k0 + scol, &sA[c * 16 * BKK]);
            gload_lds16(Bt + (size_t)(col0 + c * 16 + srow) * ld + k0 + scol, &sB[c * 16 * BKK]);
        }
        __syncthreads();
        short8 af[4], bfr[4];
        for (int m = 0; m < 4; ++m)
            af[m] = *(const short8*)&sA[(wr * 64 + m * 16 + fr) * BKK + fc];
        for (int n = 0; n < 4; ++n)
            bfr[n] = *(const short8*)&sB[(wc * 64 + n * 16 + fr) * BKK + fc];
        for (int m = 0; m < 4; ++m)
            for (int n = 0; n < 4; ++n)
                acc[m][n] = __builtin_amdgcn_mfma_f32_16x16x32_bf16(af[m], bfr[n], acc[m][n], 0, 0, 0);
        __syncthreads();
    }
    const int fq = l >> 4;
    for (int m = 0; m < 4; ++m)
        for (int n = 0; n < 4; ++n)
            for (int r = 0; r < 4; ++r) {
                int row = row0 + wr * 64 + m * 16 + fq * 4 + r;
                int col = col0 + wc * 64 + n * 16 + fr;
                float v = acc[m][n][r];
                if constexpr (__is_same(OutT, float)) C[(size_t)row * N + col] = v;
                else C[(size_t)row * N + col] = __float2bfloat16(v);
            }
}

// ---------------------------------------------------------------- fused QKV GEMM + RMSNorm + RoPE + pack
// Grid (40, 16): blockIdx.x = head slot (0..31 Q, 32..35 K, 36..39 V),
// blockIdx.y = seq block. Wave tile = 32 rows x 128 cols (acc[2][8]) so each
// thread holds a row's full head dim AND its RoPE partner (n, n+4) in-lane.
// Epilogue: in-thread sumsq + 4 shfl -> RMSNorm; in-lane RoPE; LDS-staged
// coalesced stores (V staged transposed).
__global__ __launch_bounds__(256) void gemm_qkv_fused_kernel(
    const __hip_bfloat16* __restrict__ A,    // hsb [2048][2048]
    const __hip_bfloat16* __restrict__ Bt,   // WqkvT [5120][2048]
    const float* __restrict__ cosp, const float* __restrict__ sinp,
    const float* __restrict__ qnw, const float* __restrict__ knw,
    __hip_bfloat16* __restrict__ Qh, __hip_bfloat16* __restrict__ Kh,
    __hip_bfloat16* __restrict__ Vt) {
    __shared__ __align__(16) char pool[128 * 136 * 2];            // 34816 B
    __hip_bfloat16* sA    = (__hip_bfloat16*)pool;                // [128*32] during K-loop
    __hip_bfloat16* sB    = (__hip_bfloat16*)(pool + 8192);       // [128*32]
    __hip_bfloat16* stage = (__hip_bfloat16*)pool;                // [128][136] at epilogue

    const int tid = threadIdx.x;
    const int w = tid >> 6, l = tid & 63;
    const int slot = blockIdx.x;
    const int row0 = blockIdx.y * 128;
    const int col0 = slot * 128;
    const int srow = l >> 2, scol = (l & 3) * 8;
    const int fr = l & 15, fq = l >> 4;
    const int fc = fq * 8;

    f32x4 acc[2][8] = {};
    for (int k0 = 0; k0 < 2048; k0 += BKK) {
        for (int i = 0; i < 2; ++i) {
            int c = i * 4 + w;
            gload_lds16(A + (size_t)(row0 + c * 16 + srow) * 2048 + k0 + scol, &sA[c * 16 * BKK]);
            gload_lds16(Bt + (size_t)(col0 + c * 16 + srow) * 2048 + k0 + scol, &sB[c * 16 * BKK]);
        }
        __syncthreads();
        short8 af[2], bf8[8];
        for (int m = 0; m < 2; ++m)
            af[m] = *(const short8*)&sA[(w * 32 + m * 16 + fr) * BKK + fc];
        for (int n = 0; n < 8; ++n)
            bf8[n] = *(const short8*)&sB[(n * 16 + fr) * BKK + fc];
        for (int m = 0; m < 2; ++m)
            for (int n = 0; n < 8; ++n)
                acc[m][n] = __builtin_amdgcn_mfma_f32_16x16x32_bf16(af[m], bf8[n], acc[m][n], 0, 0, 0);
        __syncthreads();
    }

    // C layout: row = w*32 + m*16 + fq*4 + r, col = n*16 + fr
    if (slot < 36) {
        const float* wgt = (slot < 32) ? qnw : knw;
        const float scl = (slot < 32) ? QK_SCALE_LOG2 : 1.0f;
        // --- RMSNorm sumsq per row: in-thread over 8 cols + shfl over 16-lane fr group
        float ssq[2][4];
        for (int m = 0; m < 2; ++m)
            for (int r = 0; r < 4; ++r) {
                float s2 = 0.f;
                for (int n = 0; n < 8; ++n) { float x = acc[m][n][r]; s2 += x * x; }
                ssq[m][r] = s2;
            }
        for (int x = 1; x < 16; x <<= 1)
            for (int m = 0; m < 2; ++m)
                for (int r = 0; r < 4; ++r)
                    ssq[m][r] += __shfl_xor(ssq[m][r], x);
        float w1[4], w2[4];
        for (int n = 0; n < 4; ++n) {
            w1[n] = wgt[n * 16 + fr];
            w2[n] = wgt[64 + n * 16 + fr];
        }
        for (int m = 0; m < 2; ++m)
            for (int r = 0; r < 4; ++r) {
                const int row = w * 32 + m * 16 + fq * 4 + r;
                const int s = row0 + row;
                const float rs = rsqrtf(ssq[m][r] * (1.0f / 128.0f) + 1e-6f);
                for (int n = 0; n < 4; ++n) {
                    float c  = cosp[(size_t)s * 128 + n * 16 + fr];
                    float sn = sinp[(size_t)s * 128 + n * 16 + fr];
                    float a = acc[m][n][r] * rs * w1[n];
                    float b = acc[m][n + 4][r] * rs * w2[n];
                    stage[row * 136 + n * 16 + fr]      = __float2bfloat16((a * c - b * sn) * scl);
                    stage[row * 136 + 64 + n * 16 + fr] = __float2bfloat16((b * c + a * sn) * scl);
                }
            }
        __syncthreads();
        const int rr = tid >> 1, hf = tid & 1;
        __hip_bfloat16* dst = (slot < 32)
            ? Qh + ((size_t)slot * SEQ + row0 + rr) * 128 + hf * 64
            : Kh + ((size_t)(slot - 32) * SEQ + row0 + rr) * 128 + hf * 64;
        for (int j = 0; j < 8; ++j)
            *(short8*)&dst[j * 8] = *(const short8*)&stage[rr * 136 + hf * 64 + j * 8];
    } else {
        // V: stage transposed [d][s_local], then coalesced store Vt[d][s]
        for (int m = 0; m < 2; ++m)
            for (int r = 0; r < 4; ++r) {
                const int row = w * 32 + m * 16 + fq * 4 + r;
                for (int n = 0; n < 8; ++n)
                    stage[(n * 16 + fr) * 136 + row] = __float2bfloat16(acc[m][n][r]);
            }
        __syncthreads();
        const int d = tid >> 1, sh = tid & 1;
        __hip_bfloat16* dst = Vt + ((size_t)(slot - 36) * 128 + d) * SEQ + row0 + sh * 64;
        for (int j = 0; j < 8; ++j)
            *(short8*)&dst[j * 8] = *(const short8*)&stage[d * 136 + sh * 64 + j * 8];
    }
}

// ---------------------------------------------------------------- causal GQA flash attention (R10: swapped QK^T)
__global__ __launch_bounds__(256, 2) void attn_kernel(
    const __hip_bfloat16* __restrict__ Qh,  // [NH][S][D], scale*log2e folded
    const __hip_bfloat16* __restrict__ Kh,  // [NKV][S][D]
    const __hip_bfloat16* __restrict__ Vt,  // [NKV][D][S]
    __hip_bfloat16* __restrict__ Oa) {      // [S][NH*D]
    __shared__ __align__(16) __hip_bfloat16 sK[2][64 * 128];   // 2 x 16 KB
    __shared__ __align__(16) __hip_bfloat16 sV[2][128 * 64];   // 2 x 16 KB
    __shared__ __align__(16) __hip_bfloat16 sP[4][16 * 72];    // per-wave P

    const int tid = threadIdx.x;
    const int w = tid >> 6, l = tid & 63;
    const int bx = blockIdx.x;
    const int y = bx & 7;                      // kv-slice -> XCD (wgid%8)
    const int qt = 127 - (bx >> 3);            // longest work first
    const int qbase = qt * 16;
    const int hkv = y >> 1;
    const int h = y * 4 + w;                   // this wave's q-head
    const int fr = l & 15, g = l >> 4;

    const __hip_bfloat16* Qp = Qh + ((size_t)h * SEQ + qbase) * HDIM;
    const __hip_bfloat16* Kp = Kh + (size_t)hkv * SEQ * HDIM;
    const __hip_bfloat16* Vp = Vt + (size_t)hkv * HDIM * SEQ;
    __hip_bfloat16* myP = &sP[w][0];

    short8 qf[4];
    for (int c = 0; c < 4; ++c)
        qf[c] = *(const short8*)&Qp[fr * HDIM + c * 32 + g * 8];

    f32x4 oacc[8] = {};
    float m_s = -3.0e38f;   // running max for q = qbase + fr
    float l_s = 0.f;        // group-partial sum for q = qbase + fr

    const int xr = (fr & 7) << 4;              // XOR-swizzle byte offset (read side)
    const int qg = qbase + fr;                 // this lane's q row (swapped layout)
    const int ntiles = ((qbase + 15) >> 6) + 1;

    auto stage = [&](int buf, int kbase) {
        for (int i = 0; i < 4; ++i) {
            int blk = i * 4 + w;               // 0..15, uniform per wave
            {   // K
                int row = blk * 4 + (l >> 4);
                int cb = ((l & 15) * 16) ^ ((row & 7) << 4);
                gload_lds16(Kp + (size_t)(kbase + row) * HDIM + (cb >> 1), &sK[buf][blk * 512]);
            }
            {   // V
                int row = blk * 8 + (l >> 3);
                int cb = ((l & 7) * 16) ^ ((row & 7) << 4);
                gload_lds16(Vp + (size_t)row * SEQ + kbase + (cb >> 1), &sV[buf][blk * 512]);
            }
        }
    };

    stage(0, 0);
    __syncthreads();                            // drains vmcnt(0): tile 0 ready

    for (int t = 0; t < ntiles; ++t) {
        const int kbase = t * 64;
        const int buf = t & 1;
        if (t + 1 < ntiles) stage(buf ^ 1, kbase + 64);   // overlap with compute

        // ---- QK^T SWAPPED: s[j][r] = S[k = kbase + j*16 + g*4 + r][q = qbase + fr]
        f32x4 s[4] = {};
        __builtin_amdgcn_s_setprio(1);
        for (int j = 0; j < 4; ++j) {
            const __hip_bfloat16* kp = &sK[buf][(j * 16 + fr) * 128];
            for (int c = 0; c < 4; ++c) {
                short8 kf = *(const short8*)&kp[((c * 64 + g * 16) ^ xr) >> 1];
                s[j] = __builtin_amdgcn_mfma_f32_16x16x32_bf16(kf, qf[c], s[j], 0, 0, 0);
            }
        }
        __builtin_amdgcn_s_setprio(0);

        // ---- causal mask (per-lane q = qg, k per reg)
        float v[4][4];
        const bool full = (kbase + 63 <= qbase);   // wave-uniform: no masking needed
        if (full) {
            for (int j = 0; j < 4; ++j)
                for (int r = 0; r < 4; ++r) v[j][r] = s[j][r];
        } else {
            const int kb0 = kbase + g * 4;
            for (int j = 0; j < 4; ++j)
                for (int r = 0; r < 4; ++r)
                    v[j][r] = (kb0 + j * 16 + r <= qg) ? s[j][r] : -1e30f;
        }
        // ---- in-lane max tree + 2-shfl cross-group reduce
        float m0 = fmaxf(fmaxf(v[0][0], v[0][1]), fmaxf(v[0][2], v[0][3]));
        float m1 = fmaxf(fmaxf(v[1][0], v[1][1]), fmaxf(v[1][2], v[1][3]));
        float m2 = fmaxf(fmaxf(v[2][0], v[2][1]), fmaxf(v[2][2], v[2][3]));
        float m3 = fmaxf(fmaxf(v[3][0], v[3][1]), fmaxf(v[3][2], v[3][3]));
        float m = fmaxf(fmaxf(m0, m1), fmaxf(m2, m3));
        m = fmaxf(m, __shfl_xor(m, 16));
        m = fmaxf(m, __shfl_xor(m, 32));
        // ---- defer-max THR=12
        if (__any(m > m_s + 12.0f)) {
            float mnew = fmaxf(m_s, m);
            float corr = fast_exp2(m_s - mnew);
            m_s = mnew;
            l_s *= corr;
            float c0 = __shfl(corr, g * 4 + 0);
            float c1 = __shfl(corr, g * 4 + 1);
            float c2 = __shfl(corr, g * 4 + 2);
            float c3 = __shfl(corr, g * 4 + 3);
            for (int dt = 0; dt < 8; ++dt) {
                oacc[dt][0] *= c0; oacc[dt][1] *= c1;
                oacc[dt][2] *= c2; oacc[dt][3] *= c3;
            }
        }
        // ---- exp2, accumulate partial sum, pack P (k-contiguous b64 writes)
        for (int j = 0; j < 4; ++j) {
            float e0 = fast_exp2(v[j][0] - m_s);
            float e1 = fast_exp2(v[j][1] - m_s);
            float e2 = fast_exp2(v[j][2] - m_s);
            float e3 = fast_exp2(v[j][3] - m_s);
            l_s += (e0 + e1) + (e2 + e3);
            short4v pw = {f2bb(e0), f2bb(e1), f2bb(e2), f2bb(e3)};
            *(short4v*)((char*)myP + fr * 144 + j * 32 + g * 8) = pw;
        }
        // ---- PV: P(16x64) x V^T(64xD) from LDS
        short8 pa0 = *(const short8*)&myP[fr * 72 + g * 8];
        short8 pa1 = *(const short8*)&myP[fr * 72 + 32 + g * 8];
        __builtin_amdgcn_s_setprio(1);
        for (int dt = 0; dt < 8; ++dt) {
            const __hip_bfloat16* vp = &sV[buf][(dt * 16 + fr) * 64];
            short8 vb0 = *(const short8*)&vp[((g * 16)      ^ xr) >> 1];
            short8 vb1 = *(const short8*)&vp[((g * 16 + 64) ^ xr) >> 1];
            oacc[dt] = __builtin_amdgcn_mfma_f32_16x16x32_bf16(pa0, vb0, oacc[dt], 0, 0, 0);
            oacc[dt] = __builtin_amdgcn_mfma_f32_16x16x32_bf16(pa1, vb1, oacc[dt], 0, 0, 0);
        }
        __builtin_amdgcn_s_setprio(0);
        __syncthreads();   // next tile staged (vmcnt 0) + all waves done with buf[t]
    }

    // ---- finalize: reduce group-partial sums, redistribute to oacc layout
    l_s += __shfl_xor(l_s, 16);
    l_s += __shfl_xor(l_s, 32);
    float inv[4];
    for (int r = 0; r < 4; ++r)
        inv[r] = 1.0f / __shfl(l_s, g * 4 + r);
    for (int dt = 0; dt < 8; ++dt)
        for (int r = 0; r < 4; ++r) {
            int qq = qbase + g * 4 + r;
            Oa[(size_t)qq * (NHEAD * HDIM) + h * HDIM + dt * 16 + fr] =
                __float2bfloat16(oacc[dt][r] * inv[r]);
        }
}

// ---------------------------------------------------------------- launch
extern "C" void kernel_launch(void* const* d_in, const int* in_sizes, int n_in,
                              void* d_out, int out_size, void* d_ws, size_t ws_size,
                              hipStream_t stream) {
    const float* hs   = (const float*)d_in[0];
    const float* cosp = (const float*)d_in[1];
    const float* sinp = (const float*)d_in[2];
    const float* wq   = (const float*)d_in[3];
    const float* wk   = (const float*)d_in[4];
    const float* wv   = (const float*)d_in[5];
    const float* wo   = (const float*)d_in[6];
    const float* qnw  = (const float*)d_in[7];
    const float* knw  = (const float*)d_in[8];
    float* out = (float*)d_out;
    char* ws = (char*)d_ws;

    // workspace timeline:
    // phase1 prep:   hsb[0,8.39M) WqkvT[8.39M,29.36M) WoT[29.36M,46.14M)
    // phase2 gemm1f: reads hsb+WqkvT; writes Qh[46.14M,62.91M) Kh[62.91M,65.01M) Vt[65.01M,67.11M)
    // phase3 attn:   reads Qh/Kh/Vt; writes Oa[8.39M,25.17M)   (over dead WqkvT)
    // phase4 gemm2:  reads Oa+WoT;   writes Qb[46.14M,71.30M)  (over dead Qh/Kh/Vt)
    __hip_bfloat16* hsb    = (__hip_bfloat16*)(ws);
    __hip_bfloat16* WqkvT  = (__hip_bfloat16*)(ws + 8388608);
    __hip_bfloat16* WoT    = (__hip_bfloat16*)(ws + 29360128);
    __hip_bfloat16* Qh     = (__hip_bfloat16*)(ws + 46137344);
    __hip_bfloat16* Kh     = (__hip_bfloat16*)(ws + 62914560);
    __hip_bfloat16* Vt     = (__hip_bfloat16*)(ws + 65011712);
    __hip_bfloat16* Oa     = (__hip_bfloat16*)(ws + 8388608);
    __hip_bfloat16* Qb     = (__hip_bfloat16*)(ws + 46137344);   // 3 x 8,388,608 B

    prep_kernel<<<22528, 256, 0, stream>>>(hs, hsb, wq, wk, wv, wo, WqkvT, WoT);
    // fused QKV projection + RMSNorm + RoPE + pack
    gemm_qkv_fused_kernel<<<dim3(40, 16), 256, 0, stream>>>(
        hsb, WqkvT, cosp, sinp, qnw, knw, Qh, Kh, Vt);
    attn_kernel<<<dim3(1024), 256, 0, stream>>>(Qh, Kh, Vt, Oa);
    // O-projection: split-K=3 (1376+1376+1344), bf16 partials (czstride = 4,194,304 elems)
    gemm_bt_kernel<__hip_bfloat16><<<dim3(16, 16, 3), 256, 0, stream>>>(
        Oa, WoT, Qb, 2048, 2048, 1376, 4096, 1376, 4194304LL, 4096);
    add3b_kernel<<<4096, 256, 0, stream>>>(Qb, Qb + 4194304, Qb + 8388608, out, (2048 * 2048) / 4);
}

// Round 12
// 209.351 us; speedup vs baseline: 1.1223x; 1.1223x over previous
//
#include <hip/hip_runtime.h>
#include <hip/hip_bf16.h>

using short4v = __attribute__((ext_vector_type(4))) short;
using short8 = __attribute__((ext_vector_type(8))) short;
using f32x4  = __attribute__((ext_vector_type(4))) float;

#define SEQ 2048
#define NHEAD 32
#define NKVH 4
#define HDIM 128
// 1/sqrt(128) * log2(e)  -- exp2-domain softmax, folded into Q at pack time
#define QK_SCALE_LOG2 (0.08838834764831845f * 1.44269504088896340f)

__device__ __forceinline__ float fast_exp2(float x) { return __builtin_amdgcn_exp2f(x); }
__device__ __forceinline__ float b2f(short u) {
    return __uint_as_float(((unsigned)(unsigned short)u) << 16);
}
__device__ __forceinline__ short f2bb(float f) {
    __hip_bfloat16 h = __float2bfloat16(f);
    return *reinterpret_cast<short*>(&h);
}
__device__ __forceinline__ void gload_lds16(const __hip_bfloat16* src, __hip_bfloat16* dst) {
    __builtin_amdgcn_global_load_lds((const __attribute__((address_space(1))) void*)src,
                                     (__attribute__((address_space(3))) void*)dst, 16, 0, 0);
}

// ---------------------------------------------------------------- fused prep: cast hs + transpose wq/wk/wv/wo
__global__ __launch_bounds__(256) void prep_kernel(
    const float* __restrict__ hs, __hip_bfloat16* __restrict__ hsb,
    const float* __restrict__ wq, const float* __restrict__ wk, const float* __restrict__ wv,
    const float* __restrict__ wo,
    __hip_bfloat16* __restrict__ WqkvT, __hip_bfloat16* __restrict__ WoT) {
    const int b = blockIdx.x, tid = threadIdx.x;
    if (b < 4096) {
        int i = b * 256 + tid;
        float4 v = ((const float4*)hs)[i];
        __hip_bfloat16 h4[4] = {__float2bfloat16(v.x), __float2bfloat16(v.y),
                                __float2bfloat16(v.z), __float2bfloat16(v.w)};
        ((ushort4*)hsb)[i] = *(ushort4*)h4;
        return;
    }
    __shared__ float tile[32][33];
    const float* W; __hip_bfloat16* Wt; int N, ld, nb, kb;
    if (b < 12288)      { int bb = b - 4096;  W = wq; Wt = WqkvT;                       N = 4096; ld = 2048; nb = (bb & 127) * 32; kb = (bb >> 7) * 32; }
    else if (b < 13312) { int bb = b - 12288; W = wk; Wt = WqkvT + (size_t)4096 * 2048; N = 512;  ld = 2048; nb = (bb & 15) * 32;  kb = (bb >> 4) * 32; }
    else if (b < 14336) { int bb = b - 13312; W = wv; Wt = WqkvT + (size_t)4608 * 2048; N = 512;  ld = 2048; nb = (bb & 15) * 32;  kb = (bb >> 4) * 32; }
    else                { int bb = b - 14336; W = wo; Wt = WoT;                         N = 2048; ld = 4096; nb = (bb & 63) * 32;  kb = (bb >> 6) * 32; }
    int tx = tid & 31, ty = tid >> 5;   // 32 x 8
    for (int j = 0; j < 32; j += 8)
        tile[ty + j][tx] = W[(size_t)(kb + ty + j) * N + nb + tx];
    __syncthreads();
    for (int j = 0; j < 32; j += 8)
        Wt[(size_t)(nb + ty + j) * ld + kb + tx] = __float2bfloat16(tile[tx][ty + j]);
}

// ---------------------------------------------------------------- 3-way bf16 partial add -> fp32 out
__global__ void add3b_kernel(const __hip_bfloat16* __restrict__ a, const __hip_bfloat16* __restrict__ b,
                             const __hip_bfloat16* __restrict__ c, float* __restrict__ o, int n4) {
    int i = blockIdx.x * blockDim.x + threadIdx.x;
    if (i >= n4) return;
    short4v x = ((const short4v*)a)[i];
    short4v y = ((const short4v*)b)[i];
    short4v z = ((const short4v*)c)[i];
    float4 r = {b2f(x[0]) + b2f(y[0]) + b2f(z[0]), b2f(x[1]) + b2f(y[1]) + b2f(z[1]),
                b2f(x[2]) + b2f(y[2]) + b2f(z[2]), b2f(x[3]) + b2f(y[3]) + b2f(z[3])};
    ((float4*)o)[i] = r;
}

// ---------------------------------------------------------------- GEMM: A(M,*)bf16 x Bt(N,*)bf16 -> C(M,N)
// BK=64, XOR-swizzled LDS: global source col pre-swizzled (cb ^= (row&7)<<4),
// linear global_load_lds dest, swizzled fragment reads -> <=2-way bank alias.
// Half the barrier drains of the BK=32 version at the same 32 KB LDS.
#define BM 128
#define BN 128
#define BK2 64
template <typename OutT>
__global__ __launch_bounds__(256) void gemm_bt_kernel(
    const __hip_bfloat16* __restrict__ A, const __hip_bfloat16* __restrict__ Bt,
    OutT* __restrict__ C, int M, int N, int KextMax, int ld, int koff, long long czstride, int Ktot) {
    const int kstart = blockIdx.z * koff;
    const int Kext = min(KextMax, Ktot - kstart);
    A  += (size_t)kstart;
    Bt += (size_t)kstart;
    C  += (size_t)blockIdx.z * czstride;
    __shared__ __align__(16) __hip_bfloat16 sA[BM * BK2];   // 16 KB
    __shared__ __align__(16) __hip_bfloat16 sB[BN * BK2];   // 16 KB
    const int tid = threadIdx.x;
    const int w = tid >> 6, l = tid & 63;
    const int wr = w >> 1, wc = w & 1;
    const int row0 = blockIdx.y * BM;
    const int col0 = blockIdx.x * BN;
    const int fr = l & 15;
    const int fq = l >> 4;
    const int xs = (fr & 7) << 4;       // read-side XOR (bytes)

    f32x4 acc[4][4] = {};

    for (int k0 = 0; k0 < Kext; k0 += BK2) {
        // stage 128x64 A and B tiles: 1024 16B-chunks each, 4 per thread.
        for (int i = 0; i < 4; ++i) {
            int ch = i * 256 + tid;                 // 0..1023
            int row = ch >> 3;                      // 0..127
            int cb = ((ch & 7) * 16) ^ ((row & 7) << 4);   // pre-swizzled source col (bytes)
            gload_lds16(A  + (size_t)(row0 + row) * ld + k0 + (cb >> 1), &sA[ch * 8]);
            gload_lds16(Bt + (size_t)(col0 + row) * ld + k0 + (cb >> 1), &sB[ch * 8]);
        }
        __syncthreads();
        short8 af[4][2], bfr[4][2];
        for (int m = 0; m < 4; ++m) {
            const char* base = (const char*)sA + (wr * 64 + m * 16 + fr) * 128;
            af[m][0] = *(const short8*)(base + (((fq) * 16)     ^ xs));
            af[m][1] = *(const short8*)(base + (((fq + 4) * 16) ^ xs));
        }
        for (int n = 0; n < 4; ++n) {
            const char* base = (const char*)sB + (wc * 64 + n * 16 + fr) * 128;
            bfr[n][0] = *(const short8*)(base + (((fq) * 16)     ^ xs));
            bfr[n][1] = *(const short8*)(base + (((fq + 4) * 16) ^ xs));
        }
        for (int kk = 0; kk < 2; ++kk)
            for (int m = 0; m < 4; ++m)
                for (int n = 0; n < 4; ++n)
                    acc[m][n] = __builtin_amdgcn_mfma_f32_16x16x32_bf16(af[m][kk], bfr[n][kk], acc[m][n], 0, 0, 0);
        __syncthreads();
    }
    for (int m = 0; m < 4; ++m)
        for (int n = 0; n < 4; ++n)
            for (int r = 0; r < 4; ++r) {
                int row = row0 + wr * 64 + m * 16 + fq * 4 + r;
                int col = col0 + wc * 64 + n * 16 + fr;
                float v = acc[m][n][r];
                if constexpr (__is_same(OutT, float)) C[(size_t)row * N + col] = v;
                else C[(size_t)row * N + col] = __float2bfloat16(v);
            }
}

// ---------------------------------------------------------------- fused partial-add + RMSNorm + RoPE + pack (vectorized)
__global__ __launch_bounds__(256) void pack_kernel(
    const __hip_bfloat16* __restrict__ P0, const __hip_bfloat16* __restrict__ P1,
    const float* __restrict__ cosp, const float* __restrict__ sinp,
    const float* __restrict__ qnw, const float* __restrict__ knw,
    __hip_bfloat16* __restrict__ Qh, __hip_bfloat16* __restrict__ Kh, __hip_bfloat16* __restrict__ Vt) {
    const int tid = threadIdx.x;
    const int rloc = tid >> 4, l16 = tid & 15;
    const int r = blockIdx.y * 16 + rloc;          // 0..79
    const int s = blockIdx.x * 2 + (r >= 40 ? 1 : 0);
    const int slot = (r >= 40) ? r - 40 : r;
    int off;
    if (slot < 32)      off = slot * 128;
    else if (slot < 36) off = 4096 + (slot - 32) * 128;
    else                off = 4608 + (slot - 36) * 128;
    const int d0 = l16 * 4;
    const size_t base = (size_t)s * 5120 + off;

    short4v a0 = *(const short4v*)&P0[base + d0];
    short4v a1 = *(const short4v*)&P0[base + d0 + 64];
    short4v b0 = *(const short4v*)&P1[base + d0];
    short4v b1 = *(const short4v*)&P1[base + d0 + 64];
    float x1[4], x2[4];
    for (int j = 0; j < 4; ++j) {
        x1[j] = b2f(a0[j]) + b2f(b0[j]);
        x2[j] = b2f(a1[j]) + b2f(b1[j]);
    }

    if (slot >= 36) {   // V: cast + transpose to (D,S)
        int t = slot - 36;
        for (int j = 0; j < 4; ++j) {
            Vt[((size_t)t * 128 + d0 + j) * SEQ + s]      = __float2bfloat16(x1[j]);
            Vt[((size_t)t * 128 + d0 + 64 + j) * SEQ + s] = __float2bfloat16(x2[j]);
        }
        return;
    }
    float ss = 0.f;
    for (int j = 0; j < 4; ++j) ss += x1[j] * x1[j] + x2[j] * x2[j];
    for (int x = 1; x < 16; x <<= 1) ss += __shfl_xor(ss, x);
    float rs = rsqrtf(ss * (1.0f / 128.0f) + 1e-6f);

    f32x4 c4 = *(const f32x4*)&cosp[(size_t)s * 128 + d0];   // cos[d]==cos[d+64]
    f32x4 s4 = *(const f32x4*)&sinp[(size_t)s * 128 + d0];
    const float* wgt = (slot < 32) ? qnw : knw;
    f32x4 w1 = *(const f32x4*)&wgt[d0];
    f32x4 w2 = *(const f32x4*)&wgt[d0 + 64];
    const float scl = (slot < 32) ? QK_SCALE_LOG2 : 1.0f;

    short4v o1, o2;
    for (int j = 0; j < 4; ++j) {
        float a = x1[j] * rs * w1[j], b = x2[j] * rs * w2[j];
        o1[j] = f2bb((a * c4[j] - b * s4[j]) * scl);
        o2[j] = f2bb((b * c4[j] + a * s4[j]) * scl);
    }
    __hip_bfloat16* dst;
    if (slot < 32) dst = Qh + ((size_t)slot * SEQ + s) * 128;
    else           dst = Kh + ((size_t)(slot - 32) * SEQ + s) * 128;
    *(short4v*)&dst[d0]      = o1;
    *(short4v*)&dst[d0 + 64] = o2;
}

// ---------------------------------------------------------------- causal GQA flash attention (swapped QK^T)
__global__ __launch_bounds__(256, 2) void attn_kernel(
    const __hip_bfloat16* __restrict__ Qh,  // [NH][S][D], scale*log2e folded
    const __hip_bfloat16* __restrict__ Kh,  // [NKV][S][D]
    const __hip_bfloat16* __restrict__ Vt,  // [NKV][D][S]
    __hip_bfloat16* __restrict__ Oa) {      // [S][NH*D]
    __shared__ __align__(16) __hip_bfloat16 sK[2][64 * 128];   // 2 x 16 KB
    __shared__ __align__(16) __hip_bfloat16 sV[2][128 * 64];   // 2 x 16 KB
    __shared__ __align__(16) __hip_bfloat16 sP[4][16 * 72];    // per-wave P

    const int tid = threadIdx.x;
    const int w = tid >> 6, l = tid & 63;
    const int bx = blockIdx.x;
    const int y = bx & 7;                      // kv-slice -> XCD (wgid%8)
    const int qt = 127 - (bx >> 3);            // longest work first
    const int qbase = qt * 16;
    const int hkv = y >> 1;
    const int h = y * 4 + w;                   // this wave's q-head
    const int fr = l & 15, g = l >> 4;

    const __hip_bfloat16* Qp = Qh + ((size_t)h * SEQ + qbase) * HDIM;
    const __hip_bfloat16* Kp = Kh + (size_t)hkv * SEQ * HDIM;
    const __hip_bfloat16* Vp = Vt + (size_t)hkv * HDIM * SEQ;
    __hip_bfloat16* myP = &sP[w][0];

    short8 qf[4];
    for (int c = 0; c < 4; ++c)
        qf[c] = *(const short8*)&Qp[fr * HDIM + c * 32 + g * 8];

    f32x4 oacc[8] = {};
    float m_s = -3.0e38f;   // running max for q = qbase + fr
    float l_s = 0.f;        // group-partial sum for q = qbase + fr

    const int xr = (fr & 7) << 4;              // XOR-swizzle byte offset (read side)
    const int qg = qbase + fr;                 // this lane's q row (swapped layout)
    const int ntiles = ((qbase + 15) >> 6) + 1;

    auto stage = [&](int buf, int kbase) {
        for (int i = 0; i < 4; ++i) {
            int blk = i * 4 + w;               // 0..15, uniform per wave
            {   // K
                int row = blk * 4 + (l >> 4);
                int cb = ((l & 15) * 16) ^ ((row & 7) << 4);
                gload_lds16(Kp + (size_t)(kbase + row) * HDIM + (cb >> 1), &sK[buf][blk * 512]);
            }
            {   // V
                int row = blk * 8 + (l >> 3);
                int cb = ((l & 7) * 16) ^ ((row & 7) << 4);
                gload_lds16(Vp + (size_t)row * SEQ + kbase + (cb >> 1), &sV[buf][blk * 512]);
            }
        }
    };

    stage(0, 0);
    __syncthreads();                            // drains vmcnt(0): tile 0 ready

    for (int t = 0; t < ntiles; ++t) {
        const int kbase = t * 64;
        const int buf = t & 1;
        if (t + 1 < ntiles) stage(buf ^ 1, kbase + 64);   // overlap with compute

        // ---- QK^T SWAPPED: s[j][r] = S[k = kbase + j*16 + g*4 + r][q = qbase + fr]
        f32x4 s[4] = {};
        __builtin_amdgcn_s_setprio(1);
        for (int j = 0; j < 4; ++j) {
            const __hip_bfloat16* kp = &sK[buf][(j * 16 + fr) * 128];
            for (int c = 0; c < 4; ++c) {
                short8 kf = *(const short8*)&kp[((c * 64 + g * 16) ^ xr) >> 1];
                s[j] = __builtin_amdgcn_mfma_f32_16x16x32_bf16(kf, qf[c], s[j], 0, 0, 0);
            }
        }
        __builtin_amdgcn_s_setprio(0);

        // ---- causal mask (per-lane q = qg, k per reg)
        float v[4][4];
        const bool full = (kbase + 63 <= qbase);   // wave-uniform: no masking needed
        if (full) {
            for (int j = 0; j < 4; ++j)
                for (int r = 0; r < 4; ++r) v[j][r] = s[j][r];
        } else {
            const int kb0 = kbase + g * 4;
            for (int j = 0; j < 4; ++j)
                for (int r = 0; r < 4; ++r)
                    v[j][r] = (kb0 + j * 16 + r <= qg) ? s[j][r] : -1e30f;
        }
        // ---- in-lane max tree + 2-shfl cross-group reduce
        float m0 = fmaxf(fmaxf(v[0][0], v[0][1]), fmaxf(v[0][2], v[0][3]));
        float m1 = fmaxf(fmaxf(v[1][0], v[1][1]), fmaxf(v[1][2], v[1][3]));
        float m2 = fmaxf(fmaxf(v[2][0], v[2][1]), fmaxf(v[2][2], v[2][3]));
        float m3 = fmaxf(fmaxf(v[3][0], v[3][1]), fmaxf(v[3][2], v[3][3]));
        float m = fmaxf(fmaxf(m0, m1), fmaxf(m2, m3));
        m = fmaxf(m, __shfl_xor(m, 16));
        m = fmaxf(m, __shfl_xor(m, 32));
        // ---- defer-max THR=12
        if (__any(m > m_s + 12.0f)) {
            float mnew = fmaxf(m_s, m);
            float corr = fast_exp2(m_s - mnew);
            m_s = mnew;
            l_s *= corr;
            float c0 = __shfl(corr, g * 4 + 0);
            float c1 = __shfl(corr, g * 4 + 1);
            float c2 = __shfl(corr, g * 4 + 2);
            float c3 = __shfl(corr, g * 4 + 3);
            for (int dt = 0; dt < 8; ++dt) {
                oacc[dt][0] *= c0; oacc[dt][1] *= c1;
                oacc[dt][2] *= c2; oacc[dt][3] *= c3;
            }
        }
        // ---- exp2, accumulate partial sum, pack P (k-contiguous b64 writes)
        for (int j = 0; j < 4; ++j) {
            float e0 = fast_exp2(v[j][0] - m_s);
            float e1 = fast_exp2(v[j][1] - m_s);
            float e2 = fast_exp2(v[j][2] - m_s);
            float e3 = fast_exp2(v[j][3] - m_s);
            l_s += (e0 + e1) + (e2 + e3);
            short4v pw = {f2bb(e0), f2bb(e1), f2bb(e2), f2bb(e3)};
            *(short4v*)((char*)myP + fr * 144 + j * 32 + g * 8) = pw;
        }
        // ---- PV: P(16x64) x V^T(64xD) from LDS
        short8 pa0 = *(const short8*)&myP[fr * 72 + g * 8];
        short8 pa1 = *(const short8*)&myP[fr * 72 + 32 + g * 8];
        __builtin_amdgcn_s_setprio(1);
        for (int dt = 0; dt < 8; ++dt) {
            const __hip_bfloat16* vp = &sV[buf][(dt * 16 + fr) * 64];
            short8 vb0 = *(const short8*)&vp[((g * 16)      ^ xr) >> 1];
            short8 vb1 = *(const short8*)&vp[((g * 16 + 64) ^ xr) >> 1];
            oacc[dt] = __builtin_amdgcn_mfma_f32_16x16x32_bf16(pa0, vb0, oacc[dt], 0, 0, 0);
            oacc[dt] = __builtin_amdgcn_mfma_f32_16x16x32_bf16(pa1, vb1, oacc[dt], 0, 0, 0);
        }
        __builtin_amdgcn_s_setprio(0);
        __syncthreads();   // next tile staged (vmcnt 0) + all waves done with buf[t]
    }

    // ---- finalize: reduce group-partial sums, redistribute to oacc layout
    l_s += __shfl_xor(l_s, 16);
    l_s += __shfl_xor(l_s, 32);
    float inv[4];
    for (int r = 0; r < 4; ++r)
        inv[r] = 1.0f / __shfl(l_s, g * 4 + r);
    for (int dt = 0; dt < 8; ++dt)
        for (int r = 0; r < 4; ++r) {
            int qq = qbase + g * 4 + r;
            Oa[(size_t)qq * (NHEAD * HDIM) + h * HDIM + dt * 16 + fr] =
                __float2bfloat16(oacc[dt][r] * inv[r]);
        }
}

// ---------------------------------------------------------------- launch
extern "C" void kernel_launch(void* const* d_in, const int* in_sizes, int n_in,
                              void* d_out, int out_size, void* d_ws, size_t ws_size,
                              hipStream_t stream) {
    const float* hs   = (const float*)d_in[0];
    const float* cosp = (const float*)d_in[1];
    const float* sinp = (const float*)d_in[2];
    const float* wq   = (const float*)d_in[3];
    const float* wk   = (const float*)d_in[4];
    const float* wv   = (const float*)d_in[5];
    const float* wo   = (const float*)d_in[6];
    const float* qnw  = (const float*)d_in[7];
    const float* knw  = (const float*)d_in[8];
    float* out = (float*)d_out;
    char* ws = (char*)d_ws;

    // workspace timeline (88,080,384 B):
    // phase1 prep:  hsb[0,8.39M) WqkvT[8.39M,29.36M) WoT[29.36M,46.14M)
    // phase2 gemm1: P0[46.14M,67.11M) P1[67.11M,88.08M)  (bf16, split-K=2)
    // phase3 pack:  Qh[8.39M,25.17M) Kh[25.17M,27.26M) Vt[27.26M,29.36M)  (over dead WqkvT)
    // phase4 attn:  Oa[46.14M,62.91M)                                     (over dead P0)
    // phase5 gemm2: Qb[0,25.17M) split-K=3 partials                       (over dead hsb/Qh/Kh/Vt)
    __hip_bfloat16* hsb    = (__hip_bfloat16*)(ws);
    __hip_bfloat16* WqkvT  = (__hip_bfloat16*)(ws + 8388608);
    __hip_bfloat16* WoT    = (__hip_bfloat16*)(ws + 29360128);
    __hip_bfloat16* P0     = (__hip_bfloat16*)(ws + 46137344);
    __hip_bfloat16* P1     = (__hip_bfloat16*)(ws + 67108864);
    __hip_bfloat16* Qh     = (__hip_bfloat16*)(ws + 8388608);
    __hip_bfloat16* Kh     = (__hip_bfloat16*)(ws + 25165824);
    __hip_bfloat16* Vt     = (__hip_bfloat16*)(ws + 27262976);
    __hip_bfloat16* Oa     = (__hip_bfloat16*)(ws + 46137344);
    __hip_bfloat16* Qb     = (__hip_bfloat16*)(ws);              // 3 x 8,388,608 B

    prep_kernel<<<22528, 256, 0, stream>>>(hs, hsb, wq, wk, wv, wo, WqkvT, WoT);
    // QKV projection, split-K=2 (K=1024 each, 16 BK64-steps), bf16 partials
    gemm_bt_kernel<__hip_bfloat16><<<dim3(40, 16, 2), 256, 0, stream>>>(
        hsb, WqkvT, P0, 2048, 5120, 1024, 2048, 1024, 10485760LL, 2048);
    pack_kernel<<<dim3(1024, 5), 256, 0, stream>>>(P0, P1, cosp, sinp, qnw, knw, Qh, Kh, Vt);
    attn_kernel<<<dim3(1024), 256, 0, stream>>>(Qh, Kh, Vt, Oa);
    // O-projection: split-K=3 (1408+1408+1280, all /64), bf16 partials
    gemm_bt_kernel<__hip_bfloat16><<<dim3(16, 16, 3), 256, 0, stream>>>(
        Oa, WoT, Qb, 2048, 2048, 1408, 4096, 1408, 4194304LL, 4096);
    add3b_kernel<<<4096, 256, 0, stream>>>(Qb, Qb + 4194304, Qb + 8388608, out, (2048 * 2048) / 4);
}